// Round 5
// baseline (645.497 us; speedup 1.0000x reference)
//
#include <hip/hip_runtime.h>
#include <hip/hip_fp16.h>

#define T_STEPS 256
#define OBS 512      // obs dim = number of independent per-row LSTMs
#define ACT 32
#define HID 1024     // output rows (hidden_dim)
#define PED 128      // pos_em_dim = LSTM hidden size
#define MSG 128      // msg_dim
#define GATES 512    // 4*PED
#define HSTR 136     // h_s row stride in halfs
#define KSTR 17      // kbuf row stride in half8 units (272B)
#define NLSTM 32
#define NATTN 224
#define L1 1.4426950408889634f
#define L2C 2.8853900817779268f
// scale folded into q~ and cb: tanh(S/sqrt(128)) = 1 - 2/(exp2(QSCALE*S)+1)
#define QSCALE 0.2550348805576823f   // 2*log2(e)/sqrt(128)

typedef _Float16 half8  __attribute__((ext_vector_type(8)));
typedef float    floatx4 __attribute__((ext_vector_type(4)));

__device__ __forceinline__ float fast_exp2(float x) { return __builtin_amdgcn_exp2f(x); }
__device__ __forceinline__ float fast_rcp(float x)  { return __builtin_amdgcn_rcpf(x); }
__device__ __forceinline__ float tanh_f(float x) {
    return fmaf(-2.0f, fast_rcp(fast_exp2(2.8853900817779268f * x) + 1.0f), 1.0f);
}

// ---------------------------------------------------------------------------
// Kernel 1: xnorm[t,n]; apre in [t][p][g] layout; zero prog counters.
// ---------------------------------------------------------------------------
__global__ void k_pre(const float* __restrict__ obs, const float* __restrict__ act,
                      const float* __restrict__ shift, const float* __restrict__ scale,
                      const float* __restrict__ W_ih, const float* __restrict__ b_ih,
                      const float* __restrict__ b_hh,
                      float* __restrict__ xnorm, float* __restrict__ apre_p,
                      int* __restrict__ prog) {
    int t = blockIdx.x;
    int tid = threadIdx.x;
    if (tid == 0 && t < 64) prog[t] = 0;
    __shared__ float a_s[ACT];
    if (tid < ACT) a_s[tid] = act[t * ACT + tid];
    __syncthreads();
    for (int n = tid; n < OBS; n += 256) {
        xnorm[t * OBS + n] = (obs[t * OBS + n] - shift[n]) / (scale[n] + 1e-8f);
    }
    for (int j = tid; j < GATES; j += 256) {
        float acc = b_ih[j] + b_hh[j];
        const float* wr = W_ih + j * 33 + 1;
#pragma unroll
        for (int u = 0; u < ACT; ++u) acc = fmaf(a_s[u], wr[u], acc);
        int g = j >> 7, p = j & 127;
        apre_p[t * GATES + p * 4 + g] = acc;
    }
}

// ---------------------------------------------------------------------------
// Kernel 2: q~[m] = QSCALE * Wk^T (Wq pe_m + bq)  (fp16), cb[m] = QSCALE * q·bk
// ---------------------------------------------------------------------------
__global__ void k_qproj(const float* __restrict__ pe, const float* __restrict__ Wq,
                        const float* __restrict__ bq, const float* __restrict__ Wk,
                        const float* __restrict__ bk,
                        _Float16* __restrict__ qh, float* __restrict__ cb) {
    int m = blockIdx.x;
    int d = threadIdx.x;  // 0..127
    __shared__ float pe_s[PED];
    __shared__ float q_s[PED];
    __shared__ float red_s[2];
    pe_s[d] = pe[m * PED + d];
    __syncthreads();
    const float* wr = Wq + d * PED;
    float a = bq[d];
#pragma unroll 8
    for (int p = 0; p < PED; ++p) a = fmaf(pe_s[p], wr[p], a);
    q_s[d] = a;
    float pb = a * bk[d];
#pragma unroll
    for (int off = 32; off; off >>= 1) pb += __shfl_xor(pb, off, 64);
    if ((d & 63) == 0) red_s[d >> 6] = pb;
    __syncthreads();
    float acc = 0.f;
#pragma unroll 8
    for (int p = 0; p < PED; ++p) acc = fmaf(q_s[p], Wk[p * PED + d], acc);
    qh[m * PED + d] = (_Float16)(acc * QSCALE);
    if (d == 0) cb[m] = (red_s[0] + red_s[1]) * QSCALE;
}

// ---------------------------------------------------------------------------
// Kernel 3 (fused): blocks 0..31 = LSTM scan producer (16 rows each),
// blocks 32..255 = attention consumers of H16[t], synced via agent-scope
// release/acquire atomics on prog[t/4] (release flushes producer L2,
// acquire invalidates consumer caches -> cross-XCD safe).
// ---------------------------------------------------------------------------
__global__ __launch_bounds__(512, 1)
void k_fused(const float* __restrict__ xnorm, const float* __restrict__ apre_p,
             const float* __restrict__ W_ih, const float* __restrict__ W_hh,
             _Float16* __restrict__ H16, int* __restrict__ prog,
             const _Float16* __restrict__ qh, const float* __restrict__ cb,
             float* __restrict__ outp) {
    __shared__ __align__(16) char smem_raw[25088];
    const int tid = threadIdx.x;

    if (blockIdx.x < NLSTM) {
        // ================= LSTM role =================
        const int lane = tid & 63, wv = tid >> 6;     // 8 waves
        const int l15 = lane & 15, quad = lane >> 4;
        const int n0 = blockIdx.x * 16;
        const int p = 16 * wv + l15;                  // h-unit this lane owns

        half8 bfr[4][4];
        float wih0[4];
#pragma unroll
        for (int g = 0; g < 4; ++g) {
            const int col = 128 * g + p;
            const float* wrow = W_hh + (size_t)col * PED;
#pragma unroll
            for (int c = 0; c < 4; ++c) {
                const int k0 = c * 32 + quad * 8;
                float4 f0 = *(const float4*)(wrow + k0);
                float4 f1 = *(const float4*)(wrow + k0 + 4);
                bfr[g][c] = (half8){(_Float16)f0.x, (_Float16)f0.y, (_Float16)f0.z, (_Float16)f0.w,
                                    (_Float16)f1.x, (_Float16)f1.y, (_Float16)f1.z, (_Float16)f1.w};
            }
            wih0[g] = W_ih[(size_t)col * 33];
        }

        _Float16* hbase = (_Float16*)smem_raw;              // 2 x 16*HSTR halfs
        float* x_s = (float*)(smem_raw + 2 * 16 * HSTR * 2);

        for (int idx = tid; idx < T_STEPS * 16; idx += 512)
            x_s[idx] = xnorm[(idx >> 4) * OBS + n0 + (idx & 15)];
        for (int idx = tid; idx < 2 * 16 * HSTR; idx += 512)
            hbase[idx] = (_Float16)0.f;

        float c_st[4] = {0.f, 0.f, 0.f, 0.f};
        const float* apl = apre_p + p * 4;
        float4 ap = *(const float4*)(apl);
        __syncthreads();

        int buf = 0;
        for (int t = 0; t < T_STEPS; ++t) {
            // ---- A-fragments from h_s
            half8 af[4];
            const _Float16* hb = hbase + buf * (16 * HSTR) + l15 * HSTR + quad * 8;
#pragma unroll
            for (int c = 0; c < 4; ++c) af[c] = *(const half8*)(hb + c * 32);

            // ---- gates via MFMA: 4 independent chains of 4
            floatx4 acc[4];
#pragma unroll
            for (int g = 0; g < 4; ++g) {
                acc[g] = (floatx4){0.f, 0.f, 0.f, 0.f};
#pragma unroll
                for (int c = 0; c < 4; ++c)
                    acc[g] = __builtin_amdgcn_mfma_f32_16x16x32_f16(
                        af[c], bfr[g][c], acc[g], 0, 0, 0);
            }

            const int tn = (t + 1 < T_STEPS) ? t + 1 : t;
            float4 ap_n = *(const float4*)(apl + tn * GATES);

            float4 x4 = *(const float4*)(x_s + t * 16 + quad * 4);
            float xr[4] = {x4.x, x4.y, x4.z, x4.w};
            float gi[4], gf[4], gg[4], go[4];
#pragma unroll
            for (int r = 0; r < 4; ++r) {
                gi[r] = fmaf(xr[r], wih0[0], acc[0][r] + ap.x);
                gf[r] = fmaf(xr[r], wih0[1], acc[1][r] + ap.y);
                gg[r] = fmaf(xr[r], wih0[2], acc[2][r] + ap.z);
                go[r] = fmaf(xr[r], wih0[3], acc[3][r] + ap.w);
            }

            // ---- batched-rcp nonlinearities (pairs of cells) ----
            float hv[4];
#pragma unroll
            for (int pr = 0; pr < 2; ++pr) {
                const int r0 = pr * 2, r1 = r0 + 1;
                float Di0 = 1.f + fast_exp2(fminf(-L1 * gi[r0], 20.f));
                float Df0 = 1.f + fast_exp2(fminf(-L1 * gf[r0], 20.f));
                float Dg0 = 1.f + fast_exp2(fminf(L2C * gg[r0], 20.f));
                float Di1 = 1.f + fast_exp2(fminf(-L1 * gi[r1], 20.f));
                float Df1 = 1.f + fast_exp2(fminf(-L1 * gf[r1], 20.f));
                float Dg1 = 1.f + fast_exp2(fminf(L2C * gg[r1], 20.f));
                float t0 = Df0 * Dg0, C0 = Di0 * t0;
                float t1 = Df1 * Dg1, C1 = Di1 * t1;
                float rp = fast_rcp(C0 * C1);
                float rA = rp * C1, rB = rp * C0;
                float iDi0 = rA * t0, iDf0 = rA * (Di0 * Dg0), iDg0 = rA * (Di0 * Df0);
                float iDi1 = rB * t1, iDf1 = rB * (Di1 * Dg1), iDg1 = rB * (Di1 * Df1);
                float cn0 = fmaf(iDf0, c_st[r0], iDi0 * fmaf(-2.f, iDg0, 1.f));
                float cn1 = fmaf(iDf1, c_st[r1], iDi1 * fmaf(-2.f, iDg1, 1.f));
                c_st[r0] = cn0; c_st[r1] = cn1;
                float Do0 = 1.f + fast_exp2(fminf(-L1 * go[r0], 20.f));
                float Do1 = 1.f + fast_exp2(fminf(-L1 * go[r1], 20.f));
                float Dc0 = 1.f + fast_exp2(fminf(L2C * cn0, 20.f));
                float Dc1 = 1.f + fast_exp2(fminf(L2C * cn1, 20.f));
                float m0 = Do0 * Dc0, m1 = Do1 * Dc1;
                float rq = fast_rcp(m0 * m1);
                float qA = rq * m1, qB = rq * m0;
                float iDo0 = qA * Dc0, iDc0 = qA * Do0;
                float iDo1 = qB * Dc1, iDc1 = qB * Do1;
                hv[r0] = iDo0 * fmaf(-2.f, iDc0, 1.f);
                hv[r1] = iDo1 * fmaf(-2.f, iDc1, 1.f);
            }

            // ---- write h to next LDS buffer + global H16
            _Float16* hn = hbase + (buf ^ 1) * (16 * HSTR);
#pragma unroll
            for (int r = 0; r < 4; ++r) {
                const int row = quad * 4 + r;
                _Float16 hh = (_Float16)hv[r];
                hn[row * HSTR + p] = hh;
                H16[(size_t)t * (OBS * MSG) + (size_t)(n0 + row) * MSG + p] = hh;
            }
            ap = ap_n;
            buf ^= 1;
            __syncthreads();
            if ((t & 3) == 3 && tid == 0)
                __hip_atomic_fetch_add(&prog[t >> 2], 1, __ATOMIC_RELEASE,
                                       __HIP_MEMORY_SCOPE_AGENT);
        }
    } else {
        // ================= ATTN role =================
        const int bid = blockIdx.x - NLSTM;           // 0..223
        half8* kbuf = (half8*)smem_raw;               // 64*KSTR half8 = 17408B
        float* s_s = (float*)(smem_raw + 64 * KSTR * 16);
        const int lane = tid & 63, wave = tid >> 6;   // 8 waves
        const int l15 = lane & 15, quad = lane >> 4;

        for (int idx = bid; idx < T_STEPS * 4; idx += NATTN) {
            const int t = idx >> 2, mq = idx & 3;

            if (tid == 0) {
                int iters = 0;
                while (__hip_atomic_load(&prog[t >> 2], __ATOMIC_ACQUIRE,
                                         __HIP_MEMORY_SCOPE_AGENT) < NLSTM) {
                    __builtin_amdgcn_s_sleep(8);
                    if (++iters > (1 << 20)) break;   // safety bail, never hit normally
                }
            }
            __syncthreads();

            // afrag: wave owns 32 m-rows (2 tiles) of quarter mq
            const int m0 = mq * 256 + wave * 32;
            half8 afrag[2][4];
            floatx4 cbv[2];
#pragma unroll
            for (int mt = 0; mt < 2; ++mt) {
                const half8* qrow = (const half8*)(qh + (size_t)(m0 + mt * 16 + l15) * PED);
#pragma unroll
                for (int c = 0; c < 4; ++c) afrag[mt][c] = qrow[c * 4 + quad];
                cbv[mt] = *(const floatx4*)(cb + m0 + mt * 16 + quad * 4);
            }

            float outacc[8];
#pragma unroll
            for (int i = 0; i < 8; ++i) outacc[i] = 0.f;

            const half8* Ht = (const half8*)(H16 + (size_t)t * (OBS * MSG));
            for (int ch = 0; ch < 8; ++ch) {
                __syncthreads();
                const half8* src = Ht + ch * 1024;
#pragma unroll
                for (int i = 0; i < 2; ++i) {
                    int f = i * 512 + tid;
                    kbuf[(f >> 4) * KSTR + (f & 15)] = src[f];
                }
                if (tid < 64) s_s[tid] = xnorm[t * OBS + ch * 64 + tid];
                __syncthreads();

#pragma unroll
                for (int nt = 0; nt < 4; ++nt) {
                    half8 bfrag[4];
#pragma unroll
                    for (int c = 0; c < 4; ++c)
                        bfrag[c] = kbuf[(nt * 16 + l15) * KSTR + c * 4 + quad];

                    floatx4 acc[2];
#pragma unroll
                    for (int mt = 0; mt < 2; ++mt) {
                        acc[mt] = cbv[mt];
#pragma unroll
                        for (int c = 0; c < 4; ++c)
                            acc[mt] = __builtin_amdgcn_mfma_f32_16x16x32_f16(
                                afrag[mt][c], bfrag[c], acc[mt], 0, 0, 0);
                    }

                    const float sv = s_s[nt * 16 + l15];
#pragma unroll
                    for (int mt = 0; mt < 2; ++mt) {
                        float E0 = fast_exp2(fminf(acc[mt][0], 20.f));
                        float E1 = fast_exp2(fminf(acc[mt][1], 20.f));
                        float E2 = fast_exp2(fminf(acc[mt][2], 20.f));
                        float E3 = fast_exp2(fminf(acc[mt][3], 20.f));
                        float D0 = 1.f + E0, D1 = 1.f + E1, D2 = 1.f + E2, D3 = 1.f + E3;
                        float m01 = D0 * D1, m23 = D2 * D3;
                        float rp = fast_rcp(m01 * m23);
                        float rA = rp * m23, rB = rp * m01;
                        float i0 = rA * D1, i1 = rA * D0, i2 = rB * D3, i3 = rB * D2;
                        outacc[mt * 4 + 0] = fmaf(fmaf(-2.f, i0, 1.f), sv, outacc[mt * 4 + 0]);
                        outacc[mt * 4 + 1] = fmaf(fmaf(-2.f, i1, 1.f), sv, outacc[mt * 4 + 1]);
                        outacc[mt * 4 + 2] = fmaf(fmaf(-2.f, i2, 1.f), sv, outacc[mt * 4 + 2]);
                        outacc[mt * 4 + 3] = fmaf(fmaf(-2.f, i3, 1.f), sv, outacc[mt * 4 + 3]);
                    }
                }
            }

#pragma unroll
            for (int i = 0; i < 8; ++i) {
                float v = outacc[i];
                v += __shfl_xor(v, 1, 16);
                v += __shfl_xor(v, 2, 16);
                v += __shfl_xor(v, 4, 16);
                v += __shfl_xor(v, 8, 16);
                outacc[i] = v;
            }
            if (l15 == 0) {
#pragma unroll
                for (int mt = 0; mt < 2; ++mt)
#pragma unroll
                    for (int r = 0; r < 4; ++r)
                        outp[(size_t)t * HID + m0 + mt * 16 + quad * 4 + r] =
                            tanh_f(outacc[mt * 4 + r]);
            }
        }
    }
}

// ---------------------------------------------------------------------------
extern "C" void kernel_launch(void* const* d_in, const int* in_sizes, int n_in,
                              void* d_out, int out_size, void* d_ws, size_t ws_size,
                              hipStream_t stream) {
    const float* obs      = (const float*)d_in[0];   // (256,512)
    const float* prev_act = (const float*)d_in[1];   // (256,32)
    const float* in_shift = (const float*)d_in[2];   // (512,)
    const float* in_scale = (const float*)d_in[3];   // (512,)
    const float* pos_emb  = (const float*)d_in[4];   // (1024,128)
    const float* W_ih     = (const float*)d_in[5];   // (512,33)
    const float* b_ih     = (const float*)d_in[6];   // (512,)
    const float* W_hh     = (const float*)d_in[7];   // (512,128)
    const float* b_hh     = (const float*)d_in[8];   // (512,)
    const float* Wq       = (const float*)d_in[9];   // (128,128)
    const float* bq       = (const float*)d_in[10];  // (128,)
    const float* Wk       = (const float*)d_in[11];  // (128,128)
    const float* bk       = (const float*)d_in[12];  // (128,)
    float* outp = (float*)d_out;                     // (256,1024)

    // workspace layout (float offsets):
    //   xnorm:  0        (131072 f)
    //   apre_p: 131072   (131072 f)
    //   qh:     262144   (131072 halfs = 65536 f)
    //   cb:     327680   (1024 f)
    //   prog:   328704   (64 int)
    //   H16:    328832   (16777216 halfs)
    float* ws = (float*)d_ws;
    float* xnorm  = ws;
    float* apre_p = ws + 131072;
    _Float16* qh  = (_Float16*)(ws + 262144);
    float* cbuf   = ws + 327680;
    int* prog     = (int*)(ws + 328704);
    _Float16* H16 = (_Float16*)(ws + 328832);

    k_pre<<<T_STEPS, 256, 0, stream>>>(obs, prev_act, in_shift, in_scale,
                                       W_ih, b_ih, b_hh, xnorm, apre_p, prog);
    k_qproj<<<HID, 128, 0, stream>>>(pos_emb, Wq, bq, Wk, bk, qh, cbuf);
    k_fused<<<NLSTM + NATTN, 512, 0, stream>>>(xnorm, apre_p, W_ih, W_hh,
                                               H16, prog, qh, cbuf, outp);
}

// Round 6
// 440.047 us; speedup vs baseline: 1.4669x; 1.4669x over previous
//
#include <hip/hip_runtime.h>
#include <hip/hip_fp16.h>

#define T_STEPS 256
#define OBS 512      // obs dim = number of independent per-row LSTMs
#define ACT 32
#define HID 1024     // output rows (hidden_dim)
#define PED 128      // pos_em_dim = LSTM hidden size
#define MSG 128      // msg_dim
#define GATES 512    // 4*PED
#define HSTR 136     // h_s row stride in halfs
#define KSTR 17      // kbuf row stride in half8 units (272B)
#define L1 1.4426950408889634f
#define L2C 2.8853900817779268f
// scale folded into q~ and cb: tanh(S/sqrt(128)) = 1 - 2/(exp2(QSCALE*S)+1)
#define QSCALE 0.2550348805576823f   // 2*log2(e)/sqrt(128)

typedef _Float16 half8  __attribute__((ext_vector_type(8)));
typedef float    floatx4 __attribute__((ext_vector_type(4)));

__device__ __forceinline__ float fast_exp2(float x) { return __builtin_amdgcn_exp2f(x); }
__device__ __forceinline__ float fast_rcp(float x)  { return __builtin_amdgcn_rcpf(x); }
__device__ __forceinline__ float tanh_f(float x) {
    return fmaf(-2.0f, fast_rcp(fast_exp2(2.8853900817779268f * x) + 1.0f), 1.0f);
}

// ---------------------------------------------------------------------------
// Kernel 1: xnorm[t,n]; apre in [t][p][g] layout:
//   apre_p[t*512 + p*4 + g] = b_ih[j]+b_hh[j]+act[t]·W_ih[j,1:],  j = 128g+p
// ---------------------------------------------------------------------------
__global__ void k_pre(const float* __restrict__ obs, const float* __restrict__ act,
                      const float* __restrict__ shift, const float* __restrict__ scale,
                      const float* __restrict__ W_ih, const float* __restrict__ b_ih,
                      const float* __restrict__ b_hh,
                      float* __restrict__ xnorm, float* __restrict__ apre_p) {
    int t = blockIdx.x;
    int tid = threadIdx.x;
    __shared__ float a_s[ACT];
    if (tid < ACT) a_s[tid] = act[t * ACT + tid];
    __syncthreads();
    for (int n = tid; n < OBS; n += 256) {
        xnorm[t * OBS + n] = (obs[t * OBS + n] - shift[n]) / (scale[n] + 1e-8f);
    }
    for (int j = tid; j < GATES; j += 256) {
        float acc = b_ih[j] + b_hh[j];
        const float* wr = W_ih + j * 33 + 1;
#pragma unroll
        for (int u = 0; u < ACT; ++u) acc = fmaf(a_s[u], wr[u], acc);
        int g = j >> 7, p = j & 127;
        apre_p[t * GATES + p * 4 + g] = acc;
    }
}

// ---------------------------------------------------------------------------
// Kernel 2: q~[m] = QSCALE * Wk^T (Wq pe_m + bq)  (fp16), cb[m] = QSCALE * q·bk
// ---------------------------------------------------------------------------
__global__ void k_qproj(const float* __restrict__ pe, const float* __restrict__ Wq,
                        const float* __restrict__ bq, const float* __restrict__ Wk,
                        const float* __restrict__ bk,
                        _Float16* __restrict__ qh, float* __restrict__ cb) {
    int m = blockIdx.x;
    int d = threadIdx.x;  // 0..127
    __shared__ float pe_s[PED];
    __shared__ float q_s[PED];
    __shared__ float red_s[2];
    pe_s[d] = pe[m * PED + d];
    __syncthreads();
    const float* wr = Wq + d * PED;
    float a = bq[d];
#pragma unroll 8
    for (int p = 0; p < PED; ++p) a = fmaf(pe_s[p], wr[p], a);
    q_s[d] = a;
    float pb = a * bk[d];
#pragma unroll
    for (int off = 32; off; off >>= 1) pb += __shfl_xor(pb, off, 64);
    if ((d & 63) == 0) red_s[d >> 6] = pb;
    __syncthreads();
    float acc = 0.f;
#pragma unroll 8
    for (int p = 0; p < PED; ++p) acc = fmaf(q_s[p], Wk[p * PED + d], acc);
    qh[m * PED + d] = (_Float16)(acc * QSCALE);
    if (d == 0) cb[m] = (red_s[0] + red_s[1]) * QSCALE;
}

// ---------------------------------------------------------------------------
// Kernel 3: LSTM scan via MFMA. 32 blocks x 512 threads (8 waves = 2/SIMD),
// 16 obs-rows/block. Wave w owns units p in [16w,16w+16): 4 gate chains of
// 4 MFMAs. All 4 gates of cell (row,p) land in ONE lane -> in-register cell
// update (batched-rcp nonlinearities). h history staged in LDS and flushed
// to H16 every 8 steps with coalesced half8 stores, so the pre-barrier
// vmcnt(0) store-drain is paid once per 8 steps, not every step.
// ---------------------------------------------------------------------------
__global__ __launch_bounds__(512, 1)
void k_lstm(const float* __restrict__ xnorm, const float* __restrict__ apre_p,
            const float* __restrict__ W_ih, const float* __restrict__ W_hh,
            _Float16* __restrict__ H16) {
    const int tid = threadIdx.x;
    const int lane = tid & 63, wv = tid >> 6;     // 8 waves
    const int l15 = lane & 15, quad = lane >> 4;
    const int n0 = blockIdx.x * 16;
    const int p = 16 * wv + l15;                  // h-unit this lane owns

    // ---- stationary B-fragments: B[n=col][k] = W_hh[col][k], col = 128g+p
    half8 bfr[4][4];
    float wih0[4];
#pragma unroll
    for (int g = 0; g < 4; ++g) {
        const int col = 128 * g + p;
        const float* wrow = W_hh + (size_t)col * PED;
#pragma unroll
        for (int c = 0; c < 4; ++c) {
            const int k0 = c * 32 + quad * 8;
            float4 f0 = *(const float4*)(wrow + k0);
            float4 f1 = *(const float4*)(wrow + k0 + 4);
            bfr[g][c] = (half8){(_Float16)f0.x, (_Float16)f0.y, (_Float16)f0.z, (_Float16)f0.w,
                                (_Float16)f1.x, (_Float16)f1.y, (_Float16)f1.z, (_Float16)f1.w};
        }
        wih0[g] = W_ih[(size_t)col * 33];
    }

    __shared__ _Float16 h_s[2][16 * HSTR];        // 8704 B
    __shared__ _Float16 h_hist[8 * 16 * MSG];     // 32768 B (8-step history)
    __shared__ float x_s[T_STEPS * 16];           // 16384 B

    for (int idx = tid; idx < T_STEPS * 16; idx += 512)
        x_s[idx] = xnorm[(idx >> 4) * OBS + n0 + (idx & 15)];
    for (int idx = tid; idx < 2 * 16 * HSTR; idx += 512)
        ((_Float16*)h_s)[idx] = (_Float16)0.f;

    float c_st[4] = {0.f, 0.f, 0.f, 0.f};
    const float* apl = apre_p + p * 4;
    float4 ap = *(const float4*)(apl);
    __syncthreads();

    int buf = 0;
    for (int t = 0; t < T_STEPS; ++t) {
        // ---- A-fragments: A[m=l15][k] from h_s (b128, conflict-free)
        half8 af[4];
        const _Float16* hb = h_s[buf] + l15 * HSTR + quad * 8;
#pragma unroll
        for (int c = 0; c < 4; ++c) af[c] = *(const half8*)(hb + c * 32);

        // ---- gates via MFMA: 4 independent chains of 4
        floatx4 acc[4];
#pragma unroll
        for (int g = 0; g < 4; ++g) {
            acc[g] = (floatx4){0.f, 0.f, 0.f, 0.f};
#pragma unroll
            for (int c = 0; c < 4; ++c)
                acc[g] = __builtin_amdgcn_mfma_f32_16x16x32_f16(
                    af[c], bfr[g][c], acc[g], 0, 0, 0);
        }

        // ---- prefetch apre for t+1 (off critical path)
        const int tn = (t + 1 < T_STEPS) ? t + 1 : t;
        float4 ap_n = *(const float4*)(apl + tn * GATES);

        float4 x4 = *(const float4*)(x_s + t * 16 + quad * 4);
        float xr[4] = {x4.x, x4.y, x4.z, x4.w};
        float gi[4], gf[4], gg[4], go[4];
#pragma unroll
        for (int r = 0; r < 4; ++r) {
            gi[r] = fmaf(xr[r], wih0[0], acc[0][r] + ap.x);
            gf[r] = fmaf(xr[r], wih0[1], acc[1][r] + ap.y);
            gg[r] = fmaf(xr[r], wih0[2], acc[2][r] + ap.z);
            go[r] = fmaf(xr[r], wih0[3], acc[3][r] + ap.w);
        }

        // ---- batched-rcp nonlinearities (pairs of cells) ----
        float hv[4];
#pragma unroll
        for (int pr = 0; pr < 2; ++pr) {
            const int r0 = pr * 2, r1 = r0 + 1;
            float Di0 = 1.f + fast_exp2(fminf(-L1 * gi[r0], 20.f));
            float Df0 = 1.f + fast_exp2(fminf(-L1 * gf[r0], 20.f));
            float Dg0 = 1.f + fast_exp2(fminf(L2C * gg[r0], 20.f));
            float Di1 = 1.f + fast_exp2(fminf(-L1 * gi[r1], 20.f));
            float Df1 = 1.f + fast_exp2(fminf(-L1 * gf[r1], 20.f));
            float Dg1 = 1.f + fast_exp2(fminf(L2C * gg[r1], 20.f));
            float t0 = Df0 * Dg0, C0 = Di0 * t0;
            float t1 = Df1 * Dg1, C1 = Di1 * t1;
            float rp = fast_rcp(C0 * C1);
            float rA = rp * C1, rB = rp * C0;
            float iDi0 = rA * t0, iDf0 = rA * (Di0 * Dg0), iDg0 = rA * (Di0 * Df0);
            float iDi1 = rB * t1, iDf1 = rB * (Di1 * Dg1), iDg1 = rB * (Di1 * Df1);
            float cn0 = fmaf(iDf0, c_st[r0], iDi0 * fmaf(-2.f, iDg0, 1.f));
            float cn1 = fmaf(iDf1, c_st[r1], iDi1 * fmaf(-2.f, iDg1, 1.f));
            c_st[r0] = cn0; c_st[r1] = cn1;
            float Do0 = 1.f + fast_exp2(fminf(-L1 * go[r0], 20.f));
            float Do1 = 1.f + fast_exp2(fminf(-L1 * go[r1], 20.f));
            float Dc0 = 1.f + fast_exp2(fminf(L2C * cn0, 20.f));
            float Dc1 = 1.f + fast_exp2(fminf(L2C * cn1, 20.f));
            float m0 = Do0 * Dc0, m1 = Do1 * Dc1;
            float rq = fast_rcp(m0 * m1);
            float qA = rq * m1, qB = rq * m0;
            float iDo0 = qA * Dc0, iDc0 = qA * Do0;
            float iDo1 = qB * Dc1, iDc1 = qB * Do1;
            hv[r0] = iDo0 * fmaf(-2.f, iDc0, 1.f);
            hv[r1] = iDo1 * fmaf(-2.f, iDc1, 1.f);
        }

        // ---- write h to next LDS buffer + history slot (LDS only!)
        _Float16* hn = h_s[buf ^ 1];
        _Float16* hh = h_hist + (t & 7) * (16 * MSG);
#pragma unroll
        for (int r = 0; r < 4; ++r) {
            const int row = quad * 4 + r;
            _Float16 hq = (_Float16)hv[r];
            hn[row * HSTR + p] = hq;
            hh[row * MSG + p] = hq;
        }
        ap = ap_n;
        buf ^= 1;
        __syncthreads();

        // ---- every 8 steps: coalesced flush of h_hist -> H16
        if ((t & 7) == 7) {
            const int tbase = t - 7;
#pragma unroll
            for (int i = 0; i < 4; ++i) {
                int e = i * 4096 + tid * 8;             // half index in [0,16384)
                int tt = e >> 11, row = (e >> 7) & 15, pp = e & 127;
                half8 v = *(const half8*)(h_hist + e);
                *(half8*)(H16 + (size_t)(tbase + tt) * (OBS * MSG)
                          + (size_t)(n0 + row) * MSG + pp) = v;
            }
        }
    }
}

// ---------------------------------------------------------------------------
// Kernel 4: attention via fp16 MFMA, S = q~·h + cb (cb folded into acc init).
//   w = 1 - 2/(exp2(S')+1);  out[t,m] = tanh(sum_n w*s[t,n])
// grid: T*4 blocks x 256 threads; K-chunk prefetched into registers;
// kbuf rows padded (KSTR); batched-rcp epilogue.
// ---------------------------------------------------------------------------
__global__ __launch_bounds__(256, 2)
void k_attn(const _Float16* __restrict__ qh, const float* __restrict__ cb,
            const _Float16* __restrict__ H16, const float* __restrict__ xnorm,
            float* __restrict__ outp) {
    const int t = blockIdx.x >> 2;
    const int mq = blockIdx.x & 3;
    const int tid = threadIdx.x;
    const int lane = tid & 63, wave = tid >> 6;
    const int l15 = lane & 15, quad = lane >> 4;
    const int m0 = mq * 256 + wave * 64;

    half8 afrag[4][4];
    floatx4 cbv[4];
#pragma unroll
    for (int mt = 0; mt < 4; ++mt) {
        const half8* qrow = (const half8*)(qh + (size_t)(m0 + mt * 16 + l15) * PED);
#pragma unroll
        for (int c = 0; c < 4; ++c) afrag[mt][c] = qrow[c * 4 + quad];
        cbv[mt] = *(const floatx4*)(cb + m0 + mt * 16 + quad * 4);
    }

    __shared__ half8 kbuf[64 * KSTR];   // 64 rows x 17 half8 (padded)
    __shared__ float s_s[64];

    float outacc[16];
#pragma unroll
    for (int i = 0; i < 16; ++i) outacc[i] = 0.f;

    const half8* Ht = (const half8*)(H16 + (size_t)t * (OBS * MSG));
    half8 pf[4];
    float sf = 0.f;
#pragma unroll
    for (int i = 0; i < 4; ++i) pf[i] = Ht[i * 256 + tid];
    if (tid < 64) sf = xnorm[t * OBS + tid];

    for (int ch = 0; ch < 8; ++ch) {
        __syncthreads();
#pragma unroll
        for (int i = 0; i < 4; ++i) {
            int f = i * 256 + tid;
            kbuf[(f >> 4) * KSTR + (f & 15)] = pf[i];
        }
        if (tid < 64) s_s[tid] = sf;
        __syncthreads();
        if (ch < 7) {
            const half8* Hn = Ht + (ch + 1) * 1024;
#pragma unroll
            for (int i = 0; i < 4; ++i) pf[i] = Hn[i * 256 + tid];
            if (tid < 64) sf = xnorm[t * OBS + (ch + 1) * 64 + tid];
        }

#pragma unroll
        for (int nt = 0; nt < 4; ++nt) {
            half8 bfrag[4];
#pragma unroll
            for (int c = 0; c < 4; ++c)
                bfrag[c] = kbuf[(nt * 16 + l15) * KSTR + c * 4 + quad];

            floatx4 acc[4];
#pragma unroll
            for (int mt = 0; mt < 4; ++mt) {
                acc[mt] = cbv[mt];
#pragma unroll
                for (int c = 0; c < 4; ++c)
                    acc[mt] = __builtin_amdgcn_mfma_f32_16x16x32_f16(
                        afrag[mt][c], bfrag[c], acc[mt], 0, 0, 0);
            }

            const float sv = s_s[nt * 16 + l15];
#pragma unroll
            for (int mt = 0; mt < 4; ++mt) {
                float E0 = fast_exp2(fminf(acc[mt][0], 20.f));
                float E1 = fast_exp2(fminf(acc[mt][1], 20.f));
                float E2 = fast_exp2(fminf(acc[mt][2], 20.f));
                float E3 = fast_exp2(fminf(acc[mt][3], 20.f));
                float D0 = 1.f + E0, D1 = 1.f + E1, D2 = 1.f + E2, D3 = 1.f + E3;
                float m01 = D0 * D1, m23 = D2 * D3;
                float rp = fast_rcp(m01 * m23);
                float rA = rp * m23, rB = rp * m01;
                float i0 = rA * D1, i1 = rA * D0, i2 = rB * D3, i3 = rB * D2;
                outacc[mt * 4 + 0] = fmaf(fmaf(-2.f, i0, 1.f), sv, outacc[mt * 4 + 0]);
                outacc[mt * 4 + 1] = fmaf(fmaf(-2.f, i1, 1.f), sv, outacc[mt * 4 + 1]);
                outacc[mt * 4 + 2] = fmaf(fmaf(-2.f, i2, 1.f), sv, outacc[mt * 4 + 2]);
                outacc[mt * 4 + 3] = fmaf(fmaf(-2.f, i3, 1.f), sv, outacc[mt * 4 + 3]);
            }
        }
    }

#pragma unroll
    for (int i = 0; i < 16; ++i) {
        float v = outacc[i];
        v += __shfl_xor(v, 1, 16);
        v += __shfl_xor(v, 2, 16);
        v += __shfl_xor(v, 4, 16);
        v += __shfl_xor(v, 8, 16);
        outacc[i] = v;
    }
    if (l15 == 0) {
        const int mbase = m0 + quad * 4;
#pragma unroll
        for (int mt = 0; mt < 4; ++mt)
#pragma unroll
            for (int r = 0; r < 4; ++r)
                outp[(size_t)t * HID + mbase + mt * 16 + r] = tanh_f(outacc[mt * 4 + r]);
    }
}

// ---------------------------------------------------------------------------
extern "C" void kernel_launch(void* const* d_in, const int* in_sizes, int n_in,
                              void* d_out, int out_size, void* d_ws, size_t ws_size,
                              hipStream_t stream) {
    const float* obs      = (const float*)d_in[0];   // (256,512)
    const float* prev_act = (const float*)d_in[1];   // (256,32)
    const float* in_shift = (const float*)d_in[2];   // (512,)
    const float* in_scale = (const float*)d_in[3];   // (512,)
    const float* pos_emb  = (const float*)d_in[4];   // (1024,128)
    const float* W_ih     = (const float*)d_in[5];   // (512,33)
    const float* b_ih     = (const float*)d_in[6];   // (512,)
    const float* W_hh     = (const float*)d_in[7];   // (512,128)
    const float* b_hh     = (const float*)d_in[8];   // (512,)
    const float* Wq       = (const float*)d_in[9];   // (128,128)
    const float* bq       = (const float*)d_in[10];  // (128,)
    const float* Wk       = (const float*)d_in[11];  // (128,128)
    const float* bk       = (const float*)d_in[12];  // (128,)
    float* outp = (float*)d_out;                     // (256,1024)

    // workspace layout (float offsets):
    //   xnorm:  0        (131072 f)
    //   apre_p: 131072   (131072 f)
    //   qh:     262144   (131072 halfs = 65536 f)
    //   cb:     327680   (1024 f)
    //   H16:    328704   (16777216 halfs)
    float* ws = (float*)d_ws;
    float* xnorm  = ws;
    float* apre_p = ws + 131072;
    _Float16* qh  = (_Float16*)(ws + 262144);
    float* cbuf   = ws + 327680;
    _Float16* H16 = (_Float16*)(ws + 328704);

    k_pre<<<T_STEPS, 256, 0, stream>>>(obs, prev_act, in_shift, in_scale,
                                       W_ih, b_ih, b_hh, xnorm, apre_p);
    k_qproj<<<HID, 128, 0, stream>>>(pos_emb, Wq, bq, Wk, bk, qh, cbuf);
    k_lstm<<<32, 512, 0, stream>>>(xnorm, apre_p, W_ih, W_hh, H16);
    k_attn<<<T_STEPS * 4, 256, 0, stream>>>(qh, cbuf, H16, xnorm, outp);
}

// Round 7
// 335.227 us; speedup vs baseline: 1.9256x; 1.3127x over previous
//
#include <hip/hip_runtime.h>
#include <hip/hip_fp16.h>

#define T_STEPS 256
#define OBS 512      // obs dim = number of independent per-row LSTMs
#define ACT 32
#define HID 1024     // output rows (hidden_dim)
#define PED 128      // pos_em_dim = LSTM hidden size
#define MSG 128      // msg_dim
#define GATES 512    // 4*PED
#define HSTR 136     // h_s row stride in halfs
#define KSTR 17      // kbuf row stride in half8 units (272B)
#define L1 1.4426950408889634f
#define L2C 2.8853900817779268f
// scale folded into q~ and cb: tanh(S/sqrt(128)) = 1 - 2/(exp2(QSCALE*S)+1)
#define QSCALE 0.2550348805576823f   // 2*log2(e)/sqrt(128)

typedef _Float16 half8  __attribute__((ext_vector_type(8)));
typedef float    floatx4 __attribute__((ext_vector_type(4)));

__device__ __forceinline__ float fast_exp2(float x) { return __builtin_amdgcn_exp2f(x); }
__device__ __forceinline__ float fast_rcp(float x)  { return __builtin_amdgcn_rcpf(x); }
__device__ __forceinline__ float tanh_f(float x) {
    return fmaf(-2.0f, fast_rcp(fast_exp2(2.8853900817779268f * x) + 1.0f), 1.0f);
}

// ---------------------------------------------------------------------------
// Kernel 1: xnorm[t,n]; apre in [t][p][g] layout:
//   apre_p[t*512 + p*4 + g] = b_ih[j]+b_hh[j]+act[t]·W_ih[j,1:],  j = 128g+p
// ---------------------------------------------------------------------------
__global__ void k_pre(const float* __restrict__ obs, const float* __restrict__ act,
                      const float* __restrict__ shift, const float* __restrict__ scale,
                      const float* __restrict__ W_ih, const float* __restrict__ b_ih,
                      const float* __restrict__ b_hh,
                      float* __restrict__ xnorm, float* __restrict__ apre_p) {
    int t = blockIdx.x;
    int tid = threadIdx.x;
    __shared__ float a_s[ACT];
    if (tid < ACT) a_s[tid] = act[t * ACT + tid];
    __syncthreads();
    for (int n = tid; n < OBS; n += 256) {
        xnorm[t * OBS + n] = (obs[t * OBS + n] - shift[n]) / (scale[n] + 1e-8f);
    }
    for (int j = tid; j < GATES; j += 256) {
        float acc = b_ih[j] + b_hh[j];
        const float* wr = W_ih + j * 33 + 1;
#pragma unroll
        for (int u = 0; u < ACT; ++u) acc = fmaf(a_s[u], wr[u], acc);
        int g = j >> 7, p = j & 127;
        apre_p[t * GATES + p * 4 + g] = acc;
    }
}

// ---------------------------------------------------------------------------
// Kernel 2: q~[m] = QSCALE * Wk^T (Wq pe_m + bq)  (fp16), cb[m] = QSCALE * q·bk
// ---------------------------------------------------------------------------
__global__ void k_qproj(const float* __restrict__ pe, const float* __restrict__ Wq,
                        const float* __restrict__ bq, const float* __restrict__ Wk,
                        const float* __restrict__ bk,
                        _Float16* __restrict__ qh, float* __restrict__ cb) {
    int m = blockIdx.x;
    int d = threadIdx.x;  // 0..127
    __shared__ float pe_s[PED];
    __shared__ float q_s[PED];
    __shared__ float red_s[2];
    pe_s[d] = pe[m * PED + d];
    __syncthreads();
    const float* wr = Wq + d * PED;
    float a = bq[d];
#pragma unroll 8
    for (int p = 0; p < PED; ++p) a = fmaf(pe_s[p], wr[p], a);
    q_s[d] = a;
    float pb = a * bk[d];
#pragma unroll
    for (int off = 32; off; off >>= 1) pb += __shfl_xor(pb, off, 64);
    if ((d & 63) == 0) red_s[d >> 6] = pb;
    __syncthreads();
    float acc = 0.f;
#pragma unroll 8
    for (int p = 0; p < PED; ++p) acc = fmaf(q_s[p], Wk[p * PED + d], acc);
    qh[m * PED + d] = (_Float16)(acc * QSCALE);
    if (d == 0) cb[m] = (red_s[0] + red_s[1]) * QSCALE;
}

// ---------------------------------------------------------------------------
// Kernel 3: LSTM scan via MFMA. 64 blocks x 512 threads (8 waves = 2/SIMD),
// 8 obs-rows/block (M-half of the 16x16 MFMA wasted, but per-CU VALU halves).
// Wave w owns units p in [16w,16w+16): 4 gate chains of 4 MFMAs. MFMA C rows
// 0..7 (the valid ones) live in quads 0,1 only, so after MFMA a shfl_xor(32)
// redistribution hands rows {2,3},{6,7} to quads 2,3 -> 2 cells/lane
// (halved cell-update VALU). Batched-rcp nonlinearities. Per-step H16 store.
// ---------------------------------------------------------------------------
__global__ __launch_bounds__(512, 1)
void k_lstm(const float* __restrict__ xnorm, const float* __restrict__ apre_p,
            const float* __restrict__ W_ih, const float* __restrict__ W_hh,
            _Float16* __restrict__ H16) {
    const int tid = threadIdx.x;
    const int lane = tid & 63, wv = tid >> 6;     // 8 waves
    const int l15 = lane & 15, quad = lane >> 4;
    const int n0 = blockIdx.x * 8;
    const int p = 16 * wv + l15;                  // h-unit this lane owns
    // 2 cells/lane: rows base, base+1 at unit p
    const int base = (quad & 1) * 4 + ((quad >> 1) * 2);  // q0:0 q1:4 q2:2 q3:6

    // ---- stationary B-fragments: B[n=col][k] = W_hh[col][k], col = 128g+p
    half8 bfr[4][4];
    float wih0[4];
#pragma unroll
    for (int g = 0; g < 4; ++g) {
        const int col = 128 * g + p;
        const float* wrow = W_hh + (size_t)col * PED;
#pragma unroll
        for (int c = 0; c < 4; ++c) {
            const int k0 = c * 32 + quad * 8;
            float4 f0 = *(const float4*)(wrow + k0);
            float4 f1 = *(const float4*)(wrow + k0 + 4);
            bfr[g][c] = (half8){(_Float16)f0.x, (_Float16)f0.y, (_Float16)f0.z, (_Float16)f0.w,
                                (_Float16)f1.x, (_Float16)f1.y, (_Float16)f1.z, (_Float16)f1.w};
        }
        wih0[g] = W_ih[(size_t)col * 33];
    }

    __shared__ _Float16 h_s[2][16 * HSTR];        // rows 8..15 stay zero forever
    __shared__ float x_s[T_STEPS * 8];            // 8 KB

    for (int idx = tid; idx < T_STEPS * 8; idx += 512)
        x_s[idx] = xnorm[(idx >> 3) * OBS + n0 + (idx & 7)];
    for (int idx = tid; idx < 2 * 16 * HSTR; idx += 512)
        ((_Float16*)h_s)[idx] = (_Float16)0.f;

    float c0 = 0.f, c1 = 0.f;
    const float* apl = apre_p + p * 4;
    float4 ap = *(const float4*)(apl);
    __syncthreads();

    int buf = 0;
    for (int t = 0; t < T_STEPS; ++t) {
        // ---- A-fragments: A[m=l15][k] from h_s (b128, conflict-free)
        half8 af[4];
        const _Float16* hb = h_s[buf] + l15 * HSTR + quad * 8;
#pragma unroll
        for (int c = 0; c < 4; ++c) af[c] = *(const half8*)(hb + c * 32);

        // ---- gates via MFMA: 4 independent chains of 4
        floatx4 acc[4];
#pragma unroll
        for (int g = 0; g < 4; ++g) {
            acc[g] = (floatx4){0.f, 0.f, 0.f, 0.f};
#pragma unroll
            for (int c = 0; c < 4; ++c)
                acc[g] = __builtin_amdgcn_mfma_f32_16x16x32_f16(
                    af[c], bfr[g][c], acc[g], 0, 0, 0);
        }

        // ---- prefetch apre for t+1 (off critical path)
        const int tn = (t + 1 < T_STEPS) ? t + 1 : t;
        float4 ap_n = *(const float4*)(apl + tn * GATES);

        // ---- redistribute: quads 2,3 take rows {2,3}/{6,7} from quads 0,1
        float gA[4], gB[4];
#pragma unroll
        for (int g = 0; g < 4; ++g) {
            float s2 = __shfl_xor(acc[g][2], 32, 64);
            float s3 = __shfl_xor(acc[g][3], 32, 64);
            gA[g] = (quad < 2) ? acc[g][0] : s2;
            gB[g] = (quad < 2) ? acc[g][1] : s3;
        }

        const float xA = x_s[t * 8 + base];
        const float xB = x_s[t * 8 + base + 1];
        float gi0 = fmaf(xA, wih0[0], gA[0] + ap.x);
        float gf0 = fmaf(xA, wih0[1], gA[1] + ap.y);
        float gg0 = fmaf(xA, wih0[2], gA[2] + ap.z);
        float go0 = fmaf(xA, wih0[3], gA[3] + ap.w);
        float gi1 = fmaf(xB, wih0[0], gB[0] + ap.x);
        float gf1 = fmaf(xB, wih0[1], gB[1] + ap.y);
        float gg1 = fmaf(xB, wih0[2], gB[2] + ap.z);
        float go1 = fmaf(xB, wih0[3], gB[3] + ap.w);

        // ---- batched-rcp nonlinearities for the 2 cells
        float Di0 = 1.f + fast_exp2(fminf(-L1 * gi0, 20.f));
        float Df0 = 1.f + fast_exp2(fminf(-L1 * gf0, 20.f));
        float Dg0 = 1.f + fast_exp2(fminf(L2C * gg0, 20.f));
        float Di1 = 1.f + fast_exp2(fminf(-L1 * gi1, 20.f));
        float Df1 = 1.f + fast_exp2(fminf(-L1 * gf1, 20.f));
        float Dg1 = 1.f + fast_exp2(fminf(L2C * gg1, 20.f));
        float t0 = Df0 * Dg0, C0 = Di0 * t0;
        float t1 = Df1 * Dg1, C1 = Di1 * t1;
        float rp = fast_rcp(C0 * C1);
        float rA = rp * C1, rB = rp * C0;
        float iDi0 = rA * t0, iDf0 = rA * (Di0 * Dg0), iDg0 = rA * (Di0 * Df0);
        float iDi1 = rB * t1, iDf1 = rB * (Di1 * Dg1), iDg1 = rB * (Di1 * Df1);
        float cn0 = fmaf(iDf0, c0, iDi0 * fmaf(-2.f, iDg0, 1.f));
        float cn1 = fmaf(iDf1, c1, iDi1 * fmaf(-2.f, iDg1, 1.f));
        c0 = cn0; c1 = cn1;
        float Do0 = 1.f + fast_exp2(fminf(-L1 * go0, 20.f));
        float Do1 = 1.f + fast_exp2(fminf(-L1 * go1, 20.f));
        float Dc0 = 1.f + fast_exp2(fminf(L2C * cn0, 20.f));
        float Dc1 = 1.f + fast_exp2(fminf(L2C * cn1, 20.f));
        float m0 = Do0 * Dc0, m1 = Do1 * Dc1;
        float rq = fast_rcp(m0 * m1);
        float qA = rq * m1, qB = rq * m0;
        float iDo0 = qA * Dc0, iDc0 = qA * Do0;
        float iDo1 = qB * Dc1, iDc1 = qB * Do1;
        _Float16 hA = (_Float16)(iDo0 * fmaf(-2.f, iDc0, 1.f));
        _Float16 hB = (_Float16)(iDo1 * fmaf(-2.f, iDc1, 1.f));

        // ---- write h to next LDS buffer + global H16 (2 stores/lane)
        _Float16* hn = h_s[buf ^ 1];
        hn[base * HSTR + p] = hA;
        hn[(base + 1) * HSTR + p] = hB;
        _Float16* Hg = H16 + (size_t)t * (OBS * MSG) + (size_t)(n0 + base) * MSG + p;
        Hg[0] = hA;
        Hg[MSG] = hB;

        ap = ap_n;
        buf ^= 1;
        __syncthreads();
    }
}

// ---------------------------------------------------------------------------
// Kernel 4: attention via fp16 MFMA, S = q~·h + cb (cb folded into acc init).
//   w = 1 - 2/(exp2(S')+1);  out[t,m] = tanh(sum_n w*s[t,n])
// grid: T*8 blocks x 256 threads (2 m-tiles/wave, 4 blocks/CU for latency
// hiding); K-chunk register prefetch; padded kbuf; batched-rcp epilogue.
// ---------------------------------------------------------------------------
__global__ __launch_bounds__(256, 4)
void k_attn(const _Float16* __restrict__ qh, const float* __restrict__ cb,
            const _Float16* __restrict__ H16, const float* __restrict__ xnorm,
            float* __restrict__ outp) {
    const int t = blockIdx.x >> 3;
    const int mq = blockIdx.x & 7;
    const int tid = threadIdx.x;
    const int lane = tid & 63, wave = tid >> 6;
    const int l15 = lane & 15, quad = lane >> 4;
    const int m0 = mq * 128 + wave * 32;

    half8 afrag[2][4];
    floatx4 cbv[2];
#pragma unroll
    for (int mt = 0; mt < 2; ++mt) {
        const half8* qrow = (const half8*)(qh + (size_t)(m0 + mt * 16 + l15) * PED);
#pragma unroll
        for (int c = 0; c < 4; ++c) afrag[mt][c] = qrow[c * 4 + quad];
        cbv[mt] = *(const floatx4*)(cb + m0 + mt * 16 + quad * 4);
    }

    __shared__ half8 kbuf[64 * KSTR];   // 64 rows x 17 half8 (padded)
    __shared__ float s_s[64];

    float outacc[8];
#pragma unroll
    for (int i = 0; i < 8; ++i) outacc[i] = 0.f;

    const half8* Ht = (const half8*)(H16 + (size_t)t * (OBS * MSG));
    half8 pf[4];
    float sf = 0.f;
#pragma unroll
    for (int i = 0; i < 4; ++i) pf[i] = Ht[i * 256 + tid];
    if (tid < 64) sf = xnorm[t * OBS + tid];

    for (int ch = 0; ch < 8; ++ch) {
        __syncthreads();
#pragma unroll
        for (int i = 0; i < 4; ++i) {
            int f = i * 256 + tid;
            kbuf[(f >> 4) * KSTR + (f & 15)] = pf[i];
        }
        if (tid < 64) s_s[tid] = sf;
        __syncthreads();
        if (ch < 7) {
            const half8* Hn = Ht + (ch + 1) * 1024;
#pragma unroll
            for (int i = 0; i < 4; ++i) pf[i] = Hn[i * 256 + tid];
            if (tid < 64) sf = xnorm[t * OBS + (ch + 1) * 64 + tid];
        }

#pragma unroll
        for (int nt = 0; nt < 4; ++nt) {
            half8 bfrag[4];
#pragma unroll
            for (int c = 0; c < 4; ++c)
                bfrag[c] = kbuf[(nt * 16 + l15) * KSTR + c * 4 + quad];

            floatx4 acc[2];
#pragma unroll
            for (int mt = 0; mt < 2; ++mt) {
                acc[mt] = cbv[mt];
#pragma unroll
                for (int c = 0; c < 4; ++c)
                    acc[mt] = __builtin_amdgcn_mfma_f32_16x16x32_f16(
                        afrag[mt][c], bfrag[c], acc[mt], 0, 0, 0);
            }

            const float sv = s_s[nt * 16 + l15];
#pragma unroll
            for (int mt = 0; mt < 2; ++mt) {
                float E0 = fast_exp2(fminf(acc[mt][0], 20.f));
                float E1 = fast_exp2(fminf(acc[mt][1], 20.f));
                float E2 = fast_exp2(fminf(acc[mt][2], 20.f));
                float E3 = fast_exp2(fminf(acc[mt][3], 20.f));
                float D0 = 1.f + E0, D1 = 1.f + E1, D2 = 1.f + E2, D3 = 1.f + E3;
                float m01 = D0 * D1, m23 = D2 * D3;
                float rp = fast_rcp(m01 * m23);
                float rA = rp * m23, rB = rp * m01;
                float i0 = rA * D1, i1 = rA * D0, i2 = rB * D3, i3 = rB * D2;
                outacc[mt * 4 + 0] = fmaf(fmaf(-2.f, i0, 1.f), sv, outacc[mt * 4 + 0]);
                outacc[mt * 4 + 1] = fmaf(fmaf(-2.f, i1, 1.f), sv, outacc[mt * 4 + 1]);
                outacc[mt * 4 + 2] = fmaf(fmaf(-2.f, i2, 1.f), sv, outacc[mt * 4 + 2]);
                outacc[mt * 4 + 3] = fmaf(fmaf(-2.f, i3, 1.f), sv, outacc[mt * 4 + 3]);
            }
        }
    }

#pragma unroll
    for (int i = 0; i < 8; ++i) {
        float v = outacc[i];
        v += __shfl_xor(v, 1, 16);
        v += __shfl_xor(v, 2, 16);
        v += __shfl_xor(v, 4, 16);
        v += __shfl_xor(v, 8, 16);
        outacc[i] = v;
    }
    if (l15 == 0) {
        const int mbase = m0 + quad * 4;
#pragma unroll
        for (int mt = 0; mt < 2; ++mt)
#pragma unroll
            for (int r = 0; r < 4; ++r)
                outp[(size_t)t * HID + mbase + mt * 16 + r] = tanh_f(outacc[mt * 4 + r]);
    }
}

// ---------------------------------------------------------------------------
extern "C" void kernel_launch(void* const* d_in, const int* in_sizes, int n_in,
                              void* d_out, int out_size, void* d_ws, size_t ws_size,
                              hipStream_t stream) {
    const float* obs      = (const float*)d_in[0];   // (256,512)
    const float* prev_act = (const float*)d_in[1];   // (256,32)
    const float* in_shift = (const float*)d_in[2];   // (512,)
    const float* in_scale = (const float*)d_in[3];   // (512,)
    const float* pos_emb  = (const float*)d_in[4];   // (1024,128)
    const float* W_ih     = (const float*)d_in[5];   // (512,33)
    const float* b_ih     = (const float*)d_in[6];   // (512,)
    const float* W_hh     = (const float*)d_in[7];   // (512,128)
    const float* b_hh     = (const float*)d_in[8];   // (512,)
    const float* Wq       = (const float*)d_in[9];   // (128,128)
    const float* bq       = (const float*)d_in[10];  // (128,)
    const float* Wk       = (const float*)d_in[11];  // (128,128)
    const float* bk       = (const float*)d_in[12];  // (128,)
    float* outp = (float*)d_out;                     // (256,1024)

    // workspace layout (float offsets):
    //   xnorm:  0        (131072 f)
    //   apre_p: 131072   (131072 f)
    //   qh:     262144   (131072 halfs = 65536 f)
    //   cb:     327680   (1024 f)
    //   H16:    328704   (16777216 halfs)
    float* ws = (float*)d_ws;
    float* xnorm  = ws;
    float* apre_p = ws + 131072;
    _Float16* qh  = (_Float16*)(ws + 262144);
    float* cbuf   = ws + 327680;
    _Float16* H16 = (_Float16*)(ws + 328704);

    k_pre<<<T_STEPS, 256, 0, stream>>>(obs, prev_act, in_shift, in_scale,
                                       W_ih, b_ih, b_hh, xnorm, apre_p);
    k_qproj<<<HID, 128, 0, stream>>>(pos_emb, Wq, bq, Wk, bk, qh, cbuf);
    k_lstm<<<64, 512, 0, stream>>>(xnorm, apre_p, W_ih, W_hh, H16);
    k_attn<<<T_STEPS * 8, 256, 0, stream>>>(qh, cbuf, H16, xnorm, outp);
}